// Round 5
// baseline (46.825 us; speedup 1.0000x reference)
//
#include <hip/hip_runtime.h>

#define B_SZ  512
#define IN_F  256
#define OUT_F 256
#define NINT  15   // GRID-1 intervals

typedef const __attribute__((address_space(1))) void gvoid_t;
typedef __attribute__((address_space(3))) void lvoid_t;

struct BpTab { float b[16]; };  // f32-arithmetic linspace (XLA/jnp semantics)

__device__ __forceinline__ float kan_eval(float wv, float xv,
                                          const float4* __restrict__ sc,
                                          const float* __restrict__ sbp, int cbase) {
    float wx = wv * xv;                       // fl32 product — ref's exact op
    float xc = fminf(fmaxf(wx, -1.0f), 1.0f);
    float u = (xc + 1.0f) * 7.5f;             // guess only; exact compares decide
    int j = (int)u;
    j = j > 15 ? 15 : j;
    // guess is within ±1 of true index (bp deviates <=1.2e-7 from uniform grid);
    // one exact-f32 compare each way implements searchsorted(right)-1 faithfully
    j += (j < 15 && xc >= sbp[j + 1]) ? 1 : 0;
    j -= (xc < sbp[j]) ? 1 : 0;               // j==0 safe: sbp[0] == -1.0f <= xc
    j = j > 14 ? 14 : j;                      // clip to G-2
    float dx = xc - sbp[j];                   // f32 sub — ref's exact op
    float4 c = sc[cbase + j];
    return __builtin_fmaf(__builtin_fmaf(__builtin_fmaf(c.w, dx, c.z), dx, c.y), dx, c.x);
}

__global__ __launch_bounds__(512, 1)
void kan_kernel(const float* __restrict__ x,
                const float* __restrict__ w,
                const float* __restrict__ bias,
                const float* __restrict__ coeffs,
                float* __restrict__ out,
                BpTab tab)
{
    __shared__ float4 sc[IN_F * NINT];  // 61440 B: coeffs[o][i][j][0..3]
    __shared__ float4 sw4[IN_F / 4];    // weights row o
    __shared__ float  sbp[16];          // f32 breakpoints (jax-f32-arith bits)

    const int o   = blockIdx.x;
    const int tid = threadIdx.x;

    // Stage coeffs[o] (61440 B) global->LDS, width-16 async, linear dest.
    const float4* gsrc = reinterpret_cast<const float4*>(coeffs) + (size_t)o * (IN_F * NINT);
    #pragma unroll
    for (int k = 0; k < 8; ++k) {
        int t = tid + k * 512;
        if (t < IN_F * NINT) {  // last pass: waves 0-3 only (wave-uniform predicate)
            __builtin_amdgcn_global_load_lds((gvoid_t*)(gsrc + t), (lvoid_t*)(sc + t), 16, 0, 0);
        }
    }
    if (tid < IN_F / 4) {
        sw4[tid] = reinterpret_cast<const float4*>(w + (size_t)o * IN_F)[tid];
    }
    if (tid < 16) {
        sbp[tid] = tab.b[tid];
    }
    __syncthreads();  // drains global_load_lds

    // One thread per batch row.
    const float4* xrow = reinterpret_cast<const float4*>(x + (size_t)tid * IN_F);
    float acc0 = 0.f, acc1 = 0.f, acc2 = 0.f, acc3 = 0.f;

    #pragma unroll 4
    for (int i4 = 0; i4 < IN_F / 4; ++i4) {
        float4 xv = xrow[i4];
        float4 wv = sw4[i4];
        int cbase = i4 * 4 * NINT;
        acc0 += kan_eval(wv.x, xv.x, sc, sbp, cbase);
        acc1 += kan_eval(wv.y, xv.y, sc, sbp, cbase + NINT);
        acc2 += kan_eval(wv.z, xv.z, sc, sbp, cbase + 2 * NINT);
        acc3 += kan_eval(wv.w, xv.w, sc, sbp, cbase + 3 * NINT);
    }

    out[(size_t)tid * OUT_F + o] = (acc0 + acc1) + (acc2 + acc3) + bias[o];
}

extern "C" void kernel_launch(void* const* d_in, const int* in_sizes, int n_in,
                              void* d_out, int out_size, void* d_ws, size_t ws_size,
                              hipStream_t stream) {
    (void)d_ws; (void)ws_size; (void)out_size;

    // Map inputs by element count (all four distinct) — proven equivalent to dict order.
    const float *x = nullptr, *wgt = nullptr, *bias = nullptr, *coeffs = nullptr;
    for (int i = 0; i < n_in; ++i) {
        switch (in_sizes[i]) {
            case 512 * 256:           x      = (const float*)d_in[i]; break;
            case 256 * 256:           wgt    = (const float*)d_in[i]; break;
            case 256:                 bias   = (const float*)d_in[i]; break;
            case 256 * 256 * 15 * 4:  coeffs = (const float*)d_in[i]; break;
            default: break;
        }
    }

    // jnp.linspace(-1, 1, 16, dtype=f32): PURE f32 arithmetic (XLA semantics):
    // delta = fl32(2/15); bp[k] = fl32(fl32(k * delta) + (-1.0f)).
    // volatile blocks host FMA contraction (variant A = no fma, XLA IEEE-strict).
    BpTab tab;
    volatile float delta = 2.0f / 15.0f;
    for (int k = 0; k < 16; ++k) {
        volatile float p = (float)k * delta;  // one f32 rounding
        tab.b[k] = p + (-1.0f);               // second f32 rounding, no contraction
    }

    kan_kernel<<<OUT_F, B_SZ, 0, stream>>>(x, wgt, bias, coeffs, (float*)d_out, tab);
}

// Round 6
// 34.752 us; speedup vs baseline: 1.3474x; 1.3474x over previous
//
#include <hip/hip_runtime.h>

#define B_SZ   512
#define IN_F   256
#define OUT_F  256
#define NINT   15
#define IHALF  128            // input features per block (IN-dim split in 2)
#define NC4    (IHALF * NINT) // float4 coeff entries per block = 1920

typedef const __attribute__((address_space(1))) void gvoid_t;
typedef __attribute__((address_space(3))) void lvoid_t;

__device__ __forceinline__ float kan_eval(float wv, float xv,
                                          const float4* __restrict__ sc, int cbase) {
    const float kD = 2.0f / 15.0f;                 // fl32(2/15), XLA's delta bits
    float wx = wv * xv;                            // ref's exact f32 product
    float xc = fminf(fmaxf(wx, -1.0f), 1.0f);
    // down-biased floor: guess error <5e-6, bias 1e-4 => i0 ∈ {j_true-1, j_true}
    float u  = __builtin_fmaf(xc, 7.5f, 7.4999f);  // u ∈ [-1e-4, 14.9999] -> i0 ∈ [0,14]
    int   i0 = (int)u;
    float f0 = (float)i0;
    // exact XLA-linspace bits: separate mul/add roundings (no contraction)
    float blo = __fadd_rn(__fmul_rn(f0, kD), -1.0f);                   // bp[i0]
    float bhi = __fadd_rn(__fmul_rn(__fadd_rn(f0, 1.0f), kD), -1.0f);  // bp[i0+1]
    bool  up = (xc >= bhi);                        // exact searchsorted(right)-1
    int   j  = i0 + (up ? 1 : 0);                  // j <= 14 automatic: bp[15] > 1 >= xc
    float bj = up ? bhi : blo;
    float dx = xc - bj;                            // ref's exact f32 sub
    float4 c = sc[cbase + j];
    return __builtin_fmaf(__builtin_fmaf(__builtin_fmaf(c.w, dx, c.z), dx, c.y), dx, c.x);
}

__global__ __launch_bounds__(512, 8)
void kan_kernel(const float* __restrict__ x,
                const float* __restrict__ w,
                const float* __restrict__ bias,
                const float* __restrict__ coeffs,
                float* __restrict__ out)
{
    __shared__ float4 sc[NC4];        // 30720 B -> 4 blocks/CU, 32 waves/CU
    __shared__ float4 sw4[IHALF / 4]; // 512 B: weights half-row

    const int o = blockIdx.x >> 1;    // output feature
    const int h = blockIdx.x & 1;     // which IN-half
    const int b = threadIdx.x;        // batch row

    // Stage this half's coeffs (30720 B) global->LDS, width-16, linear dest.
    const float4* gsrc = reinterpret_cast<const float4*>(coeffs)
                         + ((size_t)o * IN_F + h * IHALF) * NINT;
    #pragma unroll
    for (int k = 0; k < 4; ++k) {
        int t = b + k * 512;
        if (t < NC4) {  // k==3: tid<384 (6 whole waves) — wave-uniform predicate
            __builtin_amdgcn_global_load_lds((gvoid_t*)(gsrc + t), (lvoid_t*)(sc + t), 16, 0, 0);
        }
    }
    if (b < IHALF / 4) {
        sw4[b] = reinterpret_cast<const float4*>(w + (size_t)o * IN_F + h * IHALF)[b];
    }
    __syncthreads();

    const float4* xrow = reinterpret_cast<const float4*>(x + (size_t)b * IN_F + h * IHALF);
    float a0 = 0.f, a1 = 0.f, a2 = 0.f, a3 = 0.f;

    #pragma unroll 4
    for (int i4 = 0; i4 < IHALF / 4; ++i4) {
        float4 xv = xrow[i4];
        float4 wv = sw4[i4];
        int cb = i4 * 4 * NINT;
        a0 += kan_eval(wv.x, xv.x, sc, cb);
        a1 += kan_eval(wv.y, xv.y, sc, cb + NINT);
        a2 += kan_eval(wv.z, xv.z, sc, cb + 2 * NINT);
        a3 += kan_eval(wv.w, xv.w, sc, cb + 3 * NINT);
    }

    float acc = (a0 + a1) + (a2 + a3);
    if (h == 0) acc += bias[o];
    // out zeroed by memsetAsync each launch; exactly 2 commutative adds from
    // exact 0 per element -> bitwise deterministic regardless of arrival order.
    atomicAdd(out + (size_t)b * OUT_F + o, acc);
}

extern "C" void kernel_launch(void* const* d_in, const int* in_sizes, int n_in,
                              void* d_out, int out_size, void* d_ws, size_t ws_size,
                              hipStream_t stream) {
    (void)d_ws; (void)ws_size;

    const float *x = nullptr, *wgt = nullptr, *bias = nullptr, *coeffs = nullptr;
    for (int i = 0; i < n_in; ++i) {
        switch (in_sizes[i]) {
            case 512 * 256:           x      = (const float*)d_in[i]; break;
            case 256 * 256:           wgt    = (const float*)d_in[i]; break;
            case 256:                 bias   = (const float*)d_in[i]; break;
            case 256 * 256 * 15 * 4:  coeffs = (const float*)d_in[i]; break;
            default: break;
        }
    }

    hipMemsetAsync(d_out, 0, (size_t)out_size * sizeof(float), stream);
    kan_kernel<<<2 * OUT_F, B_SZ, 0, stream>>>(x, wgt, bias, coeffs, (float*)d_out);
}